// Round 10
// baseline (354.636 us; speedup 1.0000x reference)
//
#include <hip/hip_runtime.h>
#include <hip/hip_fp16.h>

#define N_NODES 100000
#define N_EDGES 1600000
#define IN_F 32
#define HID 128
#define BSHIFT 9
#define BSIZE 512
#define NBUCK 196       // ceil(100000/512)
#define EPB 8192        // edges per bucket-phase block
#define NBB 196         // ceil(E/EPB)

typedef _Float16 half8 __attribute__((ext_vector_type(8)));
typedef float floatx4 __attribute__((ext_vector_type(4)));

static __device__ __forceinline__ void pack2(_Float16* dst, float a, float b) {
    union { _Float16 h[2]; unsigned u; } p;
    p.h[0] = (_Float16)a; p.h[1] = (_Float16)b;
    *(unsigned*)dst = p.u;
}

// ---------------- CSR build (bucketed, no global per-node atomics) ----------------

__global__ void k_zero_bcnt(int* __restrict__ bcnt) {
    if (threadIdx.x < 256) bcnt[threadIdx.x] = 0;
}

__global__ __launch_bounds__(256) void k_bcount(const int* __restrict__ dst,
                                                int* __restrict__ bcnt) {
    __shared__ int hist[256];
    hist[threadIdx.x] = 0;
    __syncthreads();
    const int e0 = blockIdx.x * EPB;
#pragma unroll 4
    for (int k = 0; k < 32; ++k) {
        int e = e0 + k * 256 + threadIdx.x;
        if (e < N_EDGES) atomicAdd(&hist[dst[e] >> BSHIFT], 1);
    }
    __syncthreads();
    int c = hist[threadIdx.x];
    if (c > 0) atomicAdd(&bcnt[threadIdx.x], c);
}

__global__ __launch_bounds__(256) void k_bscan(const int* __restrict__ bcnt,
                                               int* __restrict__ bbase,
                                               int* __restrict__ bcur) {
    __shared__ int s[256];
    int v = (threadIdx.x < NBUCK) ? bcnt[threadIdx.x] : 0;
    s[threadIdx.x] = v;
    __syncthreads();
    for (int off = 1; off < 256; off <<= 1) {
        int t = (threadIdx.x >= off) ? s[threadIdx.x - off] : 0;
        __syncthreads();
        s[threadIdx.x] += t;
        __syncthreads();
    }
    if (threadIdx.x < NBUCK) {
        int ex = s[threadIdx.x] - v;
        bbase[threadIdx.x] = ex;
        bcur[threadIdx.x]  = ex;
    }
    if (threadIdx.x == 0) bbase[NBUCK] = N_EDGES;
}

__global__ __launch_bounds__(256) void k_bucket(const int* __restrict__ src,
                                                const int* __restrict__ dst,
                                                int* __restrict__ bcur,
                                                unsigned* __restrict__ rec) {
    __shared__ int hist[256];
    __shared__ int lbase[256];
    const int e0 = blockIdx.x * EPB;
    hist[threadIdx.x] = 0;
    __syncthreads();

    unsigned rk[32]; short bk[32];
#pragma unroll
    for (int k = 0; k < 32; ++k) {
        int e = e0 + k * 256 + threadIdx.x;
        if (e < N_EDGES) {
            int d = dst[e];
            int b = d >> BSHIFT;
            bk[k] = (short)b;
            rk[k] = ((unsigned)src[e] << BSHIFT) | (unsigned)(d & (BSIZE - 1));
            atomicAdd(&hist[b], 1);
        } else bk[k] = -1;
    }
    __syncthreads();
    int c = hist[threadIdx.x];
    lbase[threadIdx.x] = (c > 0) ? atomicAdd(&bcur[threadIdx.x], c) : 0;
    __syncthreads();
    hist[threadIdx.x] = 0;   // reuse as local running offset
    __syncthreads();
#pragma unroll
    for (int k = 0; k < 32; ++k) {
        if (bk[k] >= 0) {
            int off = atomicAdd(&hist[bk[k]], 1);
            rec[lbase[bk[k]] + off] = rk[k];
        }
    }
}

__global__ __launch_bounds__(256) void k_fill3(const unsigned* __restrict__ rec,
                                               const int* __restrict__ bbase,
                                               int* __restrict__ ideg,
                                               int* __restrict__ cursor,
                                               int* __restrict__ col) {
    __shared__ int lcnt[BSIZE];
    __shared__ int lcur[BSIZE];
    __shared__ int s[256];
    const int b = blockIdx.x;
    const int n0 = b << BSHIFT;
    const int rbeg = bbase[b];
    const int rend = bbase[b + 1];

    lcnt[threadIdx.x] = 0;
    lcnt[threadIdx.x + 256] = 0;
    __syncthreads();
    for (int i = rbeg + threadIdx.x; i < rend; i += 256)
        atomicAdd(&lcnt[rec[i] & (BSIZE - 1)], 1);
    __syncthreads();

    int a0 = lcnt[2 * threadIdx.x], a1 = lcnt[2 * threadIdx.x + 1];
    int pv = a0 + a1;
    s[threadIdx.x] = pv;
    __syncthreads();
    for (int off = 1; off < 256; off <<= 1) {
        int t = (threadIdx.x >= off) ? s[threadIdx.x - off] : 0;
        __syncthreads();
        s[threadIdx.x] += t;
        __syncthreads();
    }
    int ex = s[threadIdx.x] - pv;
    lcur[2 * threadIdx.x]     = rbeg + ex;
    lcur[2 * threadIdx.x + 1] = rbeg + ex + a0;
    __syncthreads();

    for (int t = threadIdx.x; t < BSIZE; t += 256) {
        int n = n0 + t;
        if (n < N_NODES) {
            ideg[n]   = lcnt[t];
            cursor[n] = lcur[t];
        }
    }
    __syncthreads();
    for (int i = rbeg + threadIdx.x; i < rend; i += 256) {
        unsigned r = rec[i];
        int slot = atomicAdd(&lcur[r & (BSIZE - 1)], 1);
        col[slot] = (int)(r >> BSHIFT);
    }
}

// ---------------- layer-1 prescale: t1 = x * dis (fp16, 32-dim) ----------------

__global__ void k_prescale(const float2* __restrict__ x, const int* __restrict__ ideg,
                           __half2* __restrict__ T) {
    int tid = blockIdx.x * 256 + threadIdx.x;
    if (tid >= N_NODES * 16) return;
    int i = tid >> 4;
    float dis = rsqrtf(1.0f + (float)ideg[i]);
    float2 v = x[tid];
    T[tid] = __floats2half2_rn(v.x * dis, v.y * dis);
}

// ---------------- gathers v3: deep unconditional full-blocks + predicated tail ----------------

// 32-dim: 16 slots x 4 feat-lanes; full blocks of 32 edges (2 rows in flight/lane).
template <bool BIAS_RELU, bool F16OUT>
__global__ __launch_bounds__(256) void k_gather32(
    const int* __restrict__ cursor, const int* __restrict__ ideg,
    const int* __restrict__ col, const _Float16* __restrict__ T,
    const float* __restrict__ b, void* __restrict__ OUTv) {
    const int lane = threadIdx.x & 63;
    const int slot = lane >> 2;
    const int fl   = lane & 3;
    const int wid  = blockIdx.x * 4 + (threadIdx.x >> 6);
    const int wstride = gridDim.x * 4;

    float bias[8];
    if constexpr (BIAS_RELU) {
        float4 bb0 = *(const float4*)(b + fl * 8);
        float4 bb1 = *(const float4*)(b + fl * 8 + 4);
        bias[0]=bb0.x; bias[1]=bb0.y; bias[2]=bb0.z; bias[3]=bb0.w;
        bias[4]=bb1.x; bias[5]=bb1.y; bias[6]=bb1.z; bias[7]=bb1.w;
    }

    for (int node = wid; node < N_NODES; node += wstride) {
        int begin = cursor[node];
        int d     = ideg[node];
        int end   = begin + d;
        float acc[8];
        if (slot == 0) {
            half8 v = *(const half8*)(T + (size_t)node * IN_F + fl * 8);
#pragma unroll
            for (int i = 0; i < 8; ++i) acc[i] = (float)v[i];
        } else {
#pragma unroll
            for (int i = 0; i < 8; ++i) acc[i] = 0.f;
        }
        int e = begin;
        int nfull = d & ~31;
        for (; e < begin + nfull; e += 32) {     // 2 unconditional rows/lane
            int s0 = col[e + slot];
            int s1 = col[e + 16 + slot];
            half8 v0 = *(const half8*)(T + (size_t)s0 * IN_F + fl * 8);
            half8 v1 = *(const half8*)(T + (size_t)s1 * IN_F + fl * 8);
#pragma unroll
            for (int i = 0; i < 8; ++i) acc[i] += (float)v0[i] + (float)v1[i];
        }
        for (; e < end; e += 16) {               // predicated tail
            int ee = e + slot;
            if (ee < end) {
                int s = col[ee];
                half8 v = *(const half8*)(T + (size_t)s * IN_F + fl * 8);
#pragma unroll
                for (int i = 0; i < 8; ++i) acc[i] += (float)v[i];
            }
        }
#pragma unroll
        for (int m = 4; m < 64; m <<= 1)
#pragma unroll
            for (int i = 0; i < 8; ++i) acc[i] += __shfl_xor(acc[i], m, 64);
        if (slot == 0) {
            float dis = rsqrtf(1.0f + (float)d);
            if constexpr (F16OUT) {
                half8 o;
#pragma unroll
                for (int i = 0; i < 8; ++i) {
                    float v = acc[i] * dis;
                    if constexpr (BIAS_RELU) { v += bias[i]; v = v > 0.f ? v : 0.f; }
                    o[i] = (_Float16)v;
                }
                *(half8*)((_Float16*)OUTv + (size_t)node * IN_F + fl * 8) = o;
            } else {
                float o[8];
#pragma unroll
                for (int i = 0; i < 8; ++i) {
                    float v = acc[i] * dis;
                    if constexpr (BIAS_RELU) { v += bias[i]; v = v > 0.f ? v : 0.f; }
                    o[i] = v;
                }
                float* op = (float*)OUTv + (size_t)node * IN_F + fl * 8;
                *(float4*)op       = make_float4(o[0], o[1], o[2], o[3]);
                *(float4*)(op + 4) = make_float4(o[4], o[5], o[6], o[7]);
            }
        }
    }
}

// 128-dim: 4 slots x 16 feat-lanes; full blocks of 16 edges (4 rows in flight/lane).
__global__ __launch_bounds__(256) void k_gather128(
    const int* __restrict__ cursor, const int* __restrict__ ideg,
    const int* __restrict__ col, const _Float16* __restrict__ T,
    const float* __restrict__ b, _Float16* __restrict__ OUT) {
    const int lane = threadIdx.x & 63;
    const int slot = lane >> 4;
    const int fl   = lane & 15;
    const int wid  = blockIdx.x * 4 + (threadIdx.x >> 6);
    const int wstride = gridDim.x * 4;

    float4 bb0 = *(const float4*)(b + fl * 8);
    float4 bb1 = *(const float4*)(b + fl * 8 + 4);
    float bias[8] = {bb0.x, bb0.y, bb0.z, bb0.w, bb1.x, bb1.y, bb1.z, bb1.w};

    for (int node = wid; node < N_NODES; node += wstride) {
        int begin = cursor[node];
        int d     = ideg[node];
        int end   = begin + d;
        float acc[8];
        if (slot == 0) {
            half8 v = *(const half8*)(T + (size_t)node * HID + fl * 8);
#pragma unroll
            for (int i = 0; i < 8; ++i) acc[i] = (float)v[i];
        } else {
#pragma unroll
            for (int i = 0; i < 8; ++i) acc[i] = 0.f;
        }
        int e = begin;
        int nfull = d & ~15;
        for (; e < begin + nfull; e += 16) {     // 4 unconditional rows/lane
            int s0 = col[e + slot];
            int s1 = col[e + 4 + slot];
            int s2 = col[e + 8 + slot];
            int s3 = col[e + 12 + slot];
            half8 v0 = *(const half8*)(T + (size_t)s0 * HID + fl * 8);
            half8 v1 = *(const half8*)(T + (size_t)s1 * HID + fl * 8);
            half8 v2 = *(const half8*)(T + (size_t)s2 * HID + fl * 8);
            half8 v3 = *(const half8*)(T + (size_t)s3 * HID + fl * 8);
#pragma unroll
            for (int i = 0; i < 8; ++i)
                acc[i] += ((float)v0[i] + (float)v1[i]) + ((float)v2[i] + (float)v3[i]);
        }
        for (; e < end; e += 4) {                // predicated tail (<16 edges)
            int ee = e + slot;
            if (ee < end) {
                int s = col[ee];
                half8 v = *(const half8*)(T + (size_t)s * HID + fl * 8);
#pragma unroll
                for (int i = 0; i < 8; ++i) acc[i] += (float)v[i];
            }
        }
#pragma unroll
        for (int m = 16; m < 64; m <<= 1)
#pragma unroll
            for (int i = 0; i < 8; ++i) acc[i] += __shfl_xor(acc[i], m, 64);
        if (slot == 0) {
            float dis = rsqrtf(1.0f + (float)d);
            half8 o;
#pragma unroll
            for (int i = 0; i < 8; ++i) {
                float v = acc[i] * dis + bias[i];
                o[i] = (_Float16)(v > 0.f ? v : 0.f);
            }
            *(half8*)(OUT + (size_t)node * HID + fl * 8) = o;
        }
    }
}

// ---------------- MFMA transforms ----------------
// 16x16x32 layouts: A[m=lane&15][k=quad*8+j], B[k=quad*8+j][n=lane&15],
// D[row=quad*4+r][col=lane&15]. Block = 4 waves x 16 rows = 64 rows.

__global__ __launch_bounds__(256) void k_xform1_mfma(
    const _Float16* __restrict__ z, const float* __restrict__ W,
    const float* __restrict__ bias, _Float16* __restrict__ Hh) {
    __shared__ _Float16 Wt[128 * 40];
    for (int idx = threadIdx.x; idx < 2048; idx += 256) {
        int n = idx & 127, k = (idx >> 7) * 2;
        pack2(&Wt[n * 40 + k], W[k * HID + n], W[(k + 1) * HID + n]);
    }
    __syncthreads();

    const int lane = threadIdx.x & 63;
    const int wave = threadIdx.x >> 6;
    const int m16 = lane & 15, quad = lane >> 4;
    const int row0 = blockIdx.x * 64 + wave * 16;
    if (row0 >= N_NODES) return;

    int arow = row0 + m16; if (arow >= N_NODES) arow = N_NODES - 1;
    half8 a = *(const half8*)(z + (size_t)arow * IN_F + quad * 8);

    floatx4 acc[8];
#pragma unroll
    for (int t = 0; t < 8; ++t) acc[t] = (floatx4){0.f, 0.f, 0.f, 0.f};
#pragma unroll
    for (int t = 0; t < 8; ++t) {
        half8 b = *(const half8*)&Wt[(t * 16 + m16) * 40 + quad * 8];
        acc[t] = __builtin_amdgcn_mfma_f32_16x16x32_f16(a, b, acc[t], 0, 0, 0);
    }
#pragma unroll
    for (int t = 0; t < 8; ++t) {
        int c = t * 16 + m16;
        float bj = bias[c];
#pragma unroll
        for (int r = 0; r < 4; ++r) {
            int row = row0 + quad * 4 + r;
            if (row < N_NODES) {
                float v = acc[t][r] + bj;
                Hh[(size_t)row * HID + c] = (_Float16)(v > 0.f ? v : 0.f);
            }
        }
    }
}

__global__ __launch_bounds__(256) void k_xform2_mfma(
    const _Float16* __restrict__ H, const float* __restrict__ W,
    const int* __restrict__ ideg, _Float16* __restrict__ T) {
    __shared__ _Float16 Wt[128 * 136];
    for (int idx = threadIdx.x; idx < 8192; idx += 256) {
        int n = idx & 127, k = (idx >> 7) * 2;
        pack2(&Wt[n * 136 + k], W[k * HID + n], W[(k + 1) * HID + n]);
    }
    __syncthreads();

    const int lane = threadIdx.x & 63;
    const int wave = threadIdx.x >> 6;
    const int m16 = lane & 15, quad = lane >> 4;
    const int row0 = blockIdx.x * 64 + wave * 16;
    if (row0 >= N_NODES) return;

    int arow = row0 + m16; if (arow >= N_NODES) arow = N_NODES - 1;
    const _Float16* hp = H + (size_t)arow * HID + quad * 8;
    half8 a[4];
#pragma unroll
    for (int kk = 0; kk < 4; ++kk) a[kk] = *(const half8*)(hp + kk * 32);

    floatx4 acc[8];
#pragma unroll
    for (int t = 0; t < 8; ++t) acc[t] = (floatx4){0.f, 0.f, 0.f, 0.f};
#pragma unroll
    for (int t = 0; t < 8; ++t) {
        const _Float16* wp = &Wt[(t * 16 + m16) * 136 + quad * 8];
#pragma unroll
        for (int kk = 0; kk < 4; ++kk) {
            half8 b = *(const half8*)(wp + kk * 32);
            acc[t] = __builtin_amdgcn_mfma_f32_16x16x32_f16(a[kk], b, acc[t], 0, 0, 0);
        }
    }
    float dis[4];
#pragma unroll
    for (int r = 0; r < 4; ++r) {
        int row = row0 + quad * 4 + r;
        dis[r] = (row < N_NODES) ? rsqrtf(1.0f + (float)ideg[row]) : 0.f;
    }
#pragma unroll
    for (int t = 0; t < 8; ++t) {
        int c = t * 16 + m16;
#pragma unroll
        for (int r = 0; r < 4; ++r) {
            int row = row0 + quad * 4 + r;
            if (row < N_NODES)
                T[(size_t)row * HID + c] = (_Float16)(acc[t][r] * dis[r]);
        }
    }
}

__global__ __launch_bounds__(256) void k_xform3_mfma(
    const _Float16* __restrict__ H, const float* __restrict__ W,
    const int* __restrict__ ideg, _Float16* __restrict__ T) {
    __shared__ _Float16 Wt[32 * 136];
    for (int idx = threadIdx.x; idx < 2048; idx += 256) {
        int n = idx & 31, k = (idx >> 5) * 2;
        pack2(&Wt[n * 136 + k], W[k * IN_F + n], W[(k + 1) * IN_F + n]);
    }
    __syncthreads();

    const int lane = threadIdx.x & 63;
    const int wave = threadIdx.x >> 6;
    const int m16 = lane & 15, quad = lane >> 4;
    const int row0 = blockIdx.x * 64 + wave * 16;
    if (row0 >= N_NODES) return;

    int arow = row0 + m16; if (arow >= N_NODES) arow = N_NODES - 1;
    const _Float16* hp = H + (size_t)arow * HID + quad * 8;
    half8 a[4];
#pragma unroll
    for (int kk = 0; kk < 4; ++kk) a[kk] = *(const half8*)(hp + kk * 32);

    floatx4 acc[2];
#pragma unroll
    for (int t = 0; t < 2; ++t) acc[t] = (floatx4){0.f, 0.f, 0.f, 0.f};
#pragma unroll
    for (int t = 0; t < 2; ++t) {
        const _Float16* wp = &Wt[(t * 16 + m16) * 136 + quad * 8];
#pragma unroll
        for (int kk = 0; kk < 4; ++kk) {
            half8 b = *(const half8*)(wp + kk * 32);
            acc[t] = __builtin_amdgcn_mfma_f32_16x16x32_f16(a[kk], b, acc[t], 0, 0, 0);
        }
    }
    float dis[4];
#pragma unroll
    for (int r = 0; r < 4; ++r) {
        int row = row0 + quad * 4 + r;
        dis[r] = (row < N_NODES) ? rsqrtf(1.0f + (float)ideg[row]) : 0.f;
    }
#pragma unroll
    for (int t = 0; t < 2; ++t) {
        int c = t * 16 + m16;
#pragma unroll
        for (int r = 0; r < 4; ++r) {
            int row = row0 + quad * 4 + r;
            if (row < N_NODES)
                T[(size_t)row * IN_F + c] = (_Float16)(acc[t][r] * dis[r]);
        }
    }
}

// ---------------- launch ----------------

extern "C" void kernel_launch(void* const* d_in, const int* in_sizes, int n_in,
                              void* d_out, int out_size, void* d_ws, size_t ws_size,
                              hipStream_t stream) {
    const float* x  = (const float*)d_in[0];
    const int*   ei = (const int*)d_in[1];
    const float* W1 = (const float*)d_in[2];
    const float* b1 = (const float*)d_in[3];
    const float* W2 = (const float*)d_in[4];
    const float* b2 = (const float*)d_in[5];
    const float* W3 = (const float*)d_in[6];
    const float* b3 = (const float*)d_in[7];
    float* out = (float*)d_out;

    const int* src = ei;             // edge_index[0]
    const int* dst = ei + N_EDGES;   // edge_index[1]

    // workspace layout (all offsets 16B-aligned)
    int*      ideg   = (int*)d_ws;                           // N (padded 102400)
    int*      cursor = ideg + 102400;                        // N
    int*      bcnt   = cursor + 102400;                      // 256
    int*      bbase  = bcnt + 256;                           // 256 (197 used)
    int*      bcur   = bbase + 256;                          // 256
    int*      col    = bcur + 256;                           // E
    unsigned* rec    = (unsigned*)(col + N_EDGES);           // E
    _Float16* t1h    = (_Float16*)(rec + N_EDGES);           // N*32 fp16 (L1 msgs)
    _Float16* z      = t1h + (size_t)N_NODES * IN_F;         // N*32 fp16
    _Float16* H1h    = z + (size_t)N_NODES * IN_F;           // N*128 fp16
    _Float16* T2h    = H1h + (size_t)N_NODES * HID;          // N*128 fp16 (reused as T3)
    _Float16* H2h    = T2h + (size_t)N_NODES * HID;          // N*128 fp16

    const int xgrid = (N_NODES + 63) / 64;   // 1563

    // ---- CSR build (bucketed; no global per-node atomics) ----
    k_zero_bcnt<<<1, 256, 0, stream>>>(bcnt);
    k_bcount<<<NBB, 256, 0, stream>>>(dst, bcnt);
    k_bscan<<<1, 256, 0, stream>>>(bcnt, bbase, bcur);
    k_bucket<<<NBB, 256, 0, stream>>>(src, dst, bcur, rec);
    k_fill3<<<NBUCK, 256, 0, stream>>>(rec, bbase, ideg, cursor, col);

    // ---- layer 1 (aggregate-first; 32-dim gather, then MFMA 32->128) ----
    k_prescale<<<(N_NODES * 16 + 255) / 256, 256, 0, stream>>>(
        (const float2*)x, ideg, (__half2*)t1h);
    k_gather32<false, true><<<2048, 256, 0, stream>>>(
        cursor, ideg, col, t1h, nullptr, z);
    k_xform1_mfma<<<xgrid, 256, 0, stream>>>(z, W1, b1, H1h);

    // ---- layer 2 (MFMA 128->128, then 128-dim fp16 gather) ----
    k_xform2_mfma<<<xgrid, 256, 0, stream>>>(H1h, W2, ideg, T2h);
    k_gather128<<<2048, 256, 0, stream>>>(cursor, ideg, col, T2h, b2, H2h);

    // ---- layer 3 (MFMA 128->32, then 32-dim fp16 gather) ----
    k_xform3_mfma<<<xgrid, 256, 0, stream>>>(H2h, W3, ideg, T2h);
    k_gather32<true, false><<<2048, 256, 0, stream>>>(
        cursor, ideg, col, T2h, b3, out);
}

// Round 11
// 336.671 us; speedup vs baseline: 1.0534x; 1.0534x over previous
//
#include <hip/hip_runtime.h>
#include <hip/hip_fp16.h>

#define N_NODES 100000
#define N_EDGES 1600000
#define IN_F 32
#define HID 128
#define BSHIFT 9
#define BSIZE 512
#define NBUCK 196       // ceil(100000/512)
#define EPB 8192        // edges per bucket-phase block
#define NBB 196         // ceil(E/EPB)

typedef _Float16 half8 __attribute__((ext_vector_type(8)));
typedef float floatx4 __attribute__((ext_vector_type(4)));

static __device__ __forceinline__ void pack2(_Float16* dst, float a, float b) {
    union { _Float16 h[2]; unsigned u; } p;
    p.h[0] = (_Float16)a; p.h[1] = (_Float16)b;
    *(unsigned*)dst = p.u;
}

// ---------------- CSR build (bucketed, no global per-node atomics) ----------------

__global__ void k_zero_bcnt(int* __restrict__ bcnt) {
    if (threadIdx.x < 256) bcnt[threadIdx.x] = 0;
}

__global__ __launch_bounds__(256) void k_bcount(const int* __restrict__ dst,
                                                int* __restrict__ bcnt) {
    __shared__ int hist[256];
    hist[threadIdx.x] = 0;
    __syncthreads();
    const int e0 = blockIdx.x * EPB;
#pragma unroll 4
    for (int k = 0; k < 32; ++k) {
        int e = e0 + k * 256 + threadIdx.x;
        if (e < N_EDGES) atomicAdd(&hist[dst[e] >> BSHIFT], 1);
    }
    __syncthreads();
    int c = hist[threadIdx.x];
    if (c > 0) atomicAdd(&bcnt[threadIdx.x], c);
}

__global__ __launch_bounds__(256) void k_bscan(const int* __restrict__ bcnt,
                                               int* __restrict__ bbase,
                                               int* __restrict__ bcur) {
    __shared__ int s[256];
    int v = (threadIdx.x < NBUCK) ? bcnt[threadIdx.x] : 0;
    s[threadIdx.x] = v;
    __syncthreads();
    for (int off = 1; off < 256; off <<= 1) {
        int t = (threadIdx.x >= off) ? s[threadIdx.x - off] : 0;
        __syncthreads();
        s[threadIdx.x] += t;
        __syncthreads();
    }
    if (threadIdx.x < NBUCK) {
        int ex = s[threadIdx.x] - v;
        bbase[threadIdx.x] = ex;
        bcur[threadIdx.x]  = ex;
    }
    if (threadIdx.x == 0) bbase[NBUCK] = N_EDGES;
}

__global__ __launch_bounds__(256) void k_bucket(const int* __restrict__ src,
                                                const int* __restrict__ dst,
                                                int* __restrict__ bcur,
                                                unsigned* __restrict__ rec) {
    __shared__ int hist[256];
    __shared__ int lbase[256];
    const int e0 = blockIdx.x * EPB;
    hist[threadIdx.x] = 0;
    __syncthreads();

    unsigned rk[32]; short bk[32];
#pragma unroll
    for (int k = 0; k < 32; ++k) {
        int e = e0 + k * 256 + threadIdx.x;
        if (e < N_EDGES) {
            int d = dst[e];
            int b = d >> BSHIFT;
            bk[k] = (short)b;
            rk[k] = ((unsigned)src[e] << BSHIFT) | (unsigned)(d & (BSIZE - 1));
            atomicAdd(&hist[b], 1);
        } else bk[k] = -1;
    }
    __syncthreads();
    int c = hist[threadIdx.x];
    lbase[threadIdx.x] = (c > 0) ? atomicAdd(&bcur[threadIdx.x], c) : 0;
    __syncthreads();
    hist[threadIdx.x] = 0;   // reuse as local running offset
    __syncthreads();
#pragma unroll
    for (int k = 0; k < 32; ++k) {
        if (bk[k] >= 0) {
            int off = atomicAdd(&hist[bk[k]], 1);
            rec[lbase[bk[k]] + off] = rk[k];
        }
    }
}

__global__ __launch_bounds__(256) void k_fill3(const unsigned* __restrict__ rec,
                                               const int* __restrict__ bbase,
                                               int* __restrict__ ideg,
                                               int* __restrict__ cursor,
                                               int* __restrict__ col) {
    __shared__ int lcnt[BSIZE];
    __shared__ int lcur[BSIZE];
    __shared__ int s[256];
    const int b = blockIdx.x;
    const int n0 = b << BSHIFT;
    const int rbeg = bbase[b];
    const int rend = bbase[b + 1];

    lcnt[threadIdx.x] = 0;
    lcnt[threadIdx.x + 256] = 0;
    __syncthreads();
    for (int i = rbeg + threadIdx.x; i < rend; i += 256)
        atomicAdd(&lcnt[rec[i] & (BSIZE - 1)], 1);
    __syncthreads();

    int a0 = lcnt[2 * threadIdx.x], a1 = lcnt[2 * threadIdx.x + 1];
    int pv = a0 + a1;
    s[threadIdx.x] = pv;
    __syncthreads();
    for (int off = 1; off < 256; off <<= 1) {
        int t = (threadIdx.x >= off) ? s[threadIdx.x - off] : 0;
        __syncthreads();
        s[threadIdx.x] += t;
        __syncthreads();
    }
    int ex = s[threadIdx.x] - pv;
    lcur[2 * threadIdx.x]     = rbeg + ex;
    lcur[2 * threadIdx.x + 1] = rbeg + ex + a0;
    __syncthreads();

    for (int t = threadIdx.x; t < BSIZE; t += 256) {
        int n = n0 + t;
        if (n < N_NODES) {
            ideg[n]   = lcnt[t];
            cursor[n] = lcur[t];
        }
    }
    __syncthreads();
    for (int i = rbeg + threadIdx.x; i < rend; i += 256) {
        unsigned r = rec[i];
        int slot = atomicAdd(&lcur[r & (BSIZE - 1)], 1);
        col[slot] = (int)(r >> BSHIFT);
    }
}

// ---------------- layer-1 prescale: t1 = x * dis (fp16, 32-dim) ----------------

__global__ void k_prescale(const float2* __restrict__ x, const int* __restrict__ ideg,
                           __half2* __restrict__ T) {
    int tid = blockIdx.x * 256 + threadIdx.x;
    if (tid >= N_NODES * 16) return;
    int i = tid >> 4;
    float dis = rsqrtf(1.0f + (float)ideg[i]);
    float2 v = x[tid];
    T[tid] = __floats2half2_rn(v.x * dis, v.y * dis);
}

// ---------------- gathers v4: deep full-blocks + ONE masked tail round trip ----------------

// 32-dim: 16 slots x 4 feat-lanes; main = 32-edge blocks (2 loads), tail = 1 masked block.
template <bool BIAS_RELU, bool F16OUT>
__global__ __launch_bounds__(256) void k_gather32(
    const int* __restrict__ cursor, const int* __restrict__ ideg,
    const int* __restrict__ col, const _Float16* __restrict__ T,
    const float* __restrict__ b, void* __restrict__ OUTv) {
    const int lane = threadIdx.x & 63;
    const int slot = lane >> 2;
    const int fl   = lane & 3;
    const int wid  = blockIdx.x * 4 + (threadIdx.x >> 6);
    const int wstride = gridDim.x * 4;

    float bias[8];
    if constexpr (BIAS_RELU) {
        float4 bb0 = *(const float4*)(b + fl * 8);
        float4 bb1 = *(const float4*)(b + fl * 8 + 4);
        bias[0]=bb0.x; bias[1]=bb0.y; bias[2]=bb0.z; bias[3]=bb0.w;
        bias[4]=bb1.x; bias[5]=bb1.y; bias[6]=bb1.z; bias[7]=bb1.w;
    }

    for (int node = wid; node < N_NODES; node += wstride) {
        int begin = cursor[node];
        int d     = ideg[node];
        int end   = begin + d;
        float acc[8];
        if (slot == 0) {
            half8 v = *(const half8*)(T + (size_t)node * IN_F + fl * 8);
#pragma unroll
            for (int i = 0; i < 8; ++i) acc[i] = (float)v[i];
        } else {
#pragma unroll
            for (int i = 0; i < 8; ++i) acc[i] = 0.f;
        }
        int e = begin;
        for (; e < begin + (d & ~31); e += 32) {   // 2 unconditional rows/lane
            int s0 = col[e + slot];
            int s1 = col[e + 16 + slot];
            half8 v0 = *(const half8*)(T + (size_t)s0 * IN_F + fl * 8);
            half8 v1 = *(const half8*)(T + (size_t)s1 * IN_F + fl * 8);
#pragma unroll
            for (int i = 0; i < 8; ++i) acc[i] += (float)v0[i] + (float)v1[i];
        }
        if (e < end) {                              // masked tail: 1 round trip
            int ee0 = e + slot, ee1 = ee0 + 16;
            int i0 = ee0 < end ? ee0 : e;
            int i1 = ee1 < end ? ee1 : e;
            float m0 = ee0 < end ? 1.f : 0.f;
            float m1 = ee1 < end ? 1.f : 0.f;
            int s0 = col[i0];
            int s1 = col[i1];
            half8 v0 = *(const half8*)(T + (size_t)s0 * IN_F + fl * 8);
            half8 v1 = *(const half8*)(T + (size_t)s1 * IN_F + fl * 8);
#pragma unroll
            for (int i = 0; i < 8; ++i) acc[i] += m0 * (float)v0[i] + m1 * (float)v1[i];
        }
#pragma unroll
        for (int m = 4; m < 64; m <<= 1)
#pragma unroll
            for (int i = 0; i < 8; ++i) acc[i] += __shfl_xor(acc[i], m, 64);
        if (slot == 0) {
            float dis = rsqrtf(1.0f + (float)d);
            if constexpr (F16OUT) {
                half8 o;
#pragma unroll
                for (int i = 0; i < 8; ++i) {
                    float v = acc[i] * dis;
                    if constexpr (BIAS_RELU) { v += bias[i]; v = v > 0.f ? v : 0.f; }
                    o[i] = (_Float16)v;
                }
                *(half8*)((_Float16*)OUTv + (size_t)node * IN_F + fl * 8) = o;
            } else {
                float o[8];
#pragma unroll
                for (int i = 0; i < 8; ++i) {
                    float v = acc[i] * dis;
                    if constexpr (BIAS_RELU) { v += bias[i]; v = v > 0.f ? v : 0.f; }
                    o[i] = v;
                }
                float* op = (float*)OUTv + (size_t)node * IN_F + fl * 8;
                *(float4*)op       = make_float4(o[0], o[1], o[2], o[3]);
                *(float4*)(op + 4) = make_float4(o[4], o[5], o[6], o[7]);
            }
        }
    }
}

// 128-dim: 4 slots x 16 feat-lanes; main = 16-edge blocks (4 loads), tail = 1 masked block.
__global__ __launch_bounds__(256) void k_gather128(
    const int* __restrict__ cursor, const int* __restrict__ ideg,
    const int* __restrict__ col, const _Float16* __restrict__ T,
    const float* __restrict__ b, _Float16* __restrict__ OUT) {
    const int lane = threadIdx.x & 63;
    const int slot = lane >> 4;
    const int fl   = lane & 15;
    const int wid  = blockIdx.x * 4 + (threadIdx.x >> 6);
    const int wstride = gridDim.x * 4;

    float4 bb0 = *(const float4*)(b + fl * 8);
    float4 bb1 = *(const float4*)(b + fl * 8 + 4);
    float bias[8] = {bb0.x, bb0.y, bb0.z, bb0.w, bb1.x, bb1.y, bb1.z, bb1.w};

    for (int node = wid; node < N_NODES; node += wstride) {
        int begin = cursor[node];
        int d     = ideg[node];
        int end   = begin + d;
        float acc[8];
        if (slot == 0) {
            half8 v = *(const half8*)(T + (size_t)node * HID + fl * 8);
#pragma unroll
            for (int i = 0; i < 8; ++i) acc[i] = (float)v[i];
        } else {
#pragma unroll
            for (int i = 0; i < 8; ++i) acc[i] = 0.f;
        }
        int e = begin;
        for (; e < begin + (d & ~15); e += 16) {   // 4 unconditional rows/lane
            int s0 = col[e + slot];
            int s1 = col[e + 4 + slot];
            int s2 = col[e + 8 + slot];
            int s3 = col[e + 12 + slot];
            half8 v0 = *(const half8*)(T + (size_t)s0 * HID + fl * 8);
            half8 v1 = *(const half8*)(T + (size_t)s1 * HID + fl * 8);
            half8 v2 = *(const half8*)(T + (size_t)s2 * HID + fl * 8);
            half8 v3 = *(const half8*)(T + (size_t)s3 * HID + fl * 8);
#pragma unroll
            for (int i = 0; i < 8; ++i)
                acc[i] += ((float)v0[i] + (float)v1[i]) + ((float)v2[i] + (float)v3[i]);
        }
        if (e < end) {                              // masked tail: 1 round trip
            int ee0 = e + slot, ee1 = ee0 + 4, ee2 = ee0 + 8, ee3 = ee0 + 12;
            int i0 = ee0 < end ? ee0 : e;
            int i1 = ee1 < end ? ee1 : e;
            int i2 = ee2 < end ? ee2 : e;
            int i3 = ee3 < end ? ee3 : e;
            float m0 = ee0 < end ? 1.f : 0.f;
            float m1 = ee1 < end ? 1.f : 0.f;
            float m2 = ee2 < end ? 1.f : 0.f;
            float m3 = ee3 < end ? 1.f : 0.f;
            int s0 = col[i0];
            int s1 = col[i1];
            int s2 = col[i2];
            int s3 = col[i3];
            half8 v0 = *(const half8*)(T + (size_t)s0 * HID + fl * 8);
            half8 v1 = *(const half8*)(T + (size_t)s1 * HID + fl * 8);
            half8 v2 = *(const half8*)(T + (size_t)s2 * HID + fl * 8);
            half8 v3 = *(const half8*)(T + (size_t)s3 * HID + fl * 8);
#pragma unroll
            for (int i = 0; i < 8; ++i)
                acc[i] += (m0 * (float)v0[i] + m1 * (float)v1[i]) +
                          (m2 * (float)v2[i] + m3 * (float)v3[i]);
        }
#pragma unroll
        for (int m = 16; m < 64; m <<= 1)
#pragma unroll
            for (int i = 0; i < 8; ++i) acc[i] += __shfl_xor(acc[i], m, 64);
        if (slot == 0) {
            float dis = rsqrtf(1.0f + (float)d);
            half8 o;
#pragma unroll
            for (int i = 0; i < 8; ++i) {
                float v = acc[i] * dis + bias[i];
                o[i] = (_Float16)(v > 0.f ? v : 0.f);
            }
            *(half8*)(OUT + (size_t)node * HID + fl * 8) = o;
        }
    }
}

// ---------------- MFMA transforms ----------------
// 16x16x32 layouts: A[m=lane&15][k=quad*8+j], B[k=quad*8+j][n=lane&15],
// D[row=quad*4+r][col=lane&15]. Block = 4 waves x 16 rows = 64 rows.

__global__ __launch_bounds__(256) void k_xform1_mfma(
    const _Float16* __restrict__ z, const float* __restrict__ W,
    const float* __restrict__ bias, _Float16* __restrict__ Hh) {
    __shared__ _Float16 Wt[128 * 40];
    for (int idx = threadIdx.x; idx < 2048; idx += 256) {
        int n = idx & 127, k = (idx >> 7) * 2;
        pack2(&Wt[n * 40 + k], W[k * HID + n], W[(k + 1) * HID + n]);
    }
    __syncthreads();

    const int lane = threadIdx.x & 63;
    const int wave = threadIdx.x >> 6;
    const int m16 = lane & 15, quad = lane >> 4;
    const int row0 = blockIdx.x * 64 + wave * 16;
    if (row0 >= N_NODES) return;

    int arow = row0 + m16; if (arow >= N_NODES) arow = N_NODES - 1;
    half8 a = *(const half8*)(z + (size_t)arow * IN_F + quad * 8);

    floatx4 acc[8];
#pragma unroll
    for (int t = 0; t < 8; ++t) acc[t] = (floatx4){0.f, 0.f, 0.f, 0.f};
#pragma unroll
    for (int t = 0; t < 8; ++t) {
        half8 b = *(const half8*)&Wt[(t * 16 + m16) * 40 + quad * 8];
        acc[t] = __builtin_amdgcn_mfma_f32_16x16x32_f16(a, b, acc[t], 0, 0, 0);
    }
#pragma unroll
    for (int t = 0; t < 8; ++t) {
        int c = t * 16 + m16;
        float bj = bias[c];
#pragma unroll
        for (int r = 0; r < 4; ++r) {
            int row = row0 + quad * 4 + r;
            if (row < N_NODES) {
                float v = acc[t][r] + bj;
                Hh[(size_t)row * HID + c] = (_Float16)(v > 0.f ? v : 0.f);
            }
        }
    }
}

__global__ __launch_bounds__(256) void k_xform2_mfma(
    const _Float16* __restrict__ H, const float* __restrict__ W,
    const int* __restrict__ ideg, _Float16* __restrict__ T) {
    __shared__ _Float16 Wt[128 * 136];
    for (int idx = threadIdx.x; idx < 8192; idx += 256) {
        int n = idx & 127, k = (idx >> 7) * 2;
        pack2(&Wt[n * 136 + k], W[k * HID + n], W[(k + 1) * HID + n]);
    }
    __syncthreads();

    const int lane = threadIdx.x & 63;
    const int wave = threadIdx.x >> 6;
    const int m16 = lane & 15, quad = lane >> 4;
    const int row0 = blockIdx.x * 64 + wave * 16;
    if (row0 >= N_NODES) return;

    int arow = row0 + m16; if (arow >= N_NODES) arow = N_NODES - 1;
    const _Float16* hp = H + (size_t)arow * HID + quad * 8;
    half8 a[4];
#pragma unroll
    for (int kk = 0; kk < 4; ++kk) a[kk] = *(const half8*)(hp + kk * 32);

    floatx4 acc[8];
#pragma unroll
    for (int t = 0; t < 8; ++t) acc[t] = (floatx4){0.f, 0.f, 0.f, 0.f};
#pragma unroll
    for (int t = 0; t < 8; ++t) {
        const _Float16* wp = &Wt[(t * 16 + m16) * 136 + quad * 8];
#pragma unroll
        for (int kk = 0; kk < 4; ++kk) {
            half8 b = *(const half8*)(wp + kk * 32);
            acc[t] = __builtin_amdgcn_mfma_f32_16x16x32_f16(a[kk], b, acc[t], 0, 0, 0);
        }
    }
    float dis[4];
#pragma unroll
    for (int r = 0; r < 4; ++r) {
        int row = row0 + quad * 4 + r;
        dis[r] = (row < N_NODES) ? rsqrtf(1.0f + (float)ideg[row]) : 0.f;
    }
#pragma unroll
    for (int t = 0; t < 8; ++t) {
        int c = t * 16 + m16;
#pragma unroll
        for (int r = 0; r < 4; ++r) {
            int row = row0 + quad * 4 + r;
            if (row < N_NODES)
                T[(size_t)row * HID + c] = (_Float16)(acc[t][r] * dis[r]);
        }
    }
}

__global__ __launch_bounds__(256) void k_xform3_mfma(
    const _Float16* __restrict__ H, const float* __restrict__ W,
    const int* __restrict__ ideg, _Float16* __restrict__ T) {
    __shared__ _Float16 Wt[32 * 136];
    for (int idx = threadIdx.x; idx < 2048; idx += 256) {
        int n = idx & 31, k = (idx >> 5) * 2;
        pack2(&Wt[n * 136 + k], W[k * IN_F + n], W[(k + 1) * IN_F + n]);
    }
    __syncthreads();

    const int lane = threadIdx.x & 63;
    const int wave = threadIdx.x >> 6;
    const int m16 = lane & 15, quad = lane >> 4;
    const int row0 = blockIdx.x * 64 + wave * 16;
    if (row0 >= N_NODES) return;

    int arow = row0 + m16; if (arow >= N_NODES) arow = N_NODES - 1;
    const _Float16* hp = H + (size_t)arow * HID + quad * 8;
    half8 a[4];
#pragma unroll
    for (int kk = 0; kk < 4; ++kk) a[kk] = *(const half8*)(hp + kk * 32);

    floatx4 acc[2];
#pragma unroll
    for (int t = 0; t < 2; ++t) acc[t] = (floatx4){0.f, 0.f, 0.f, 0.f};
#pragma unroll
    for (int t = 0; t < 2; ++t) {
        const _Float16* wp = &Wt[(t * 16 + m16) * 136 + quad * 8];
#pragma unroll
        for (int kk = 0; kk < 4; ++kk) {
            half8 b = *(const half8*)(wp + kk * 32);
            acc[t] = __builtin_amdgcn_mfma_f32_16x16x32_f16(a[kk], b, acc[t], 0, 0, 0);
        }
    }
    float dis[4];
#pragma unroll
    for (int r = 0; r < 4; ++r) {
        int row = row0 + quad * 4 + r;
        dis[r] = (row < N_NODES) ? rsqrtf(1.0f + (float)ideg[row]) : 0.f;
    }
#pragma unroll
    for (int t = 0; t < 2; ++t) {
        int c = t * 16 + m16;
#pragma unroll
        for (int r = 0; r < 4; ++r) {
            int row = row0 + quad * 4 + r;
            if (row < N_NODES)
                T[(size_t)row * IN_F + c] = (_Float16)(acc[t][r] * dis[r]);
        }
    }
}

// ---------------- launch ----------------

extern "C" void kernel_launch(void* const* d_in, const int* in_sizes, int n_in,
                              void* d_out, int out_size, void* d_ws, size_t ws_size,
                              hipStream_t stream) {
    const float* x  = (const float*)d_in[0];
    const int*   ei = (const int*)d_in[1];
    const float* W1 = (const float*)d_in[2];
    const float* b1 = (const float*)d_in[3];
    const float* W2 = (const float*)d_in[4];
    const float* b2 = (const float*)d_in[5];
    const float* W3 = (const float*)d_in[6];
    const float* b3 = (const float*)d_in[7];
    float* out = (float*)d_out;

    const int* src = ei;             // edge_index[0]
    const int* dst = ei + N_EDGES;   // edge_index[1]

    // workspace layout (all offsets 16B-aligned)
    int*      ideg   = (int*)d_ws;                           // N (padded 102400)
    int*      cursor = ideg + 102400;                        // N
    int*      bcnt   = cursor + 102400;                      // 256
    int*      bbase  = bcnt + 256;                           // 256 (197 used)
    int*      bcur   = bbase + 256;                          // 256
    int*      col    = bcur + 256;                           // E
    unsigned* rec    = (unsigned*)(col + N_EDGES);           // E
    _Float16* t1h    = (_Float16*)(rec + N_EDGES);           // N*32 fp16 (L1 msgs)
    _Float16* z      = t1h + (size_t)N_NODES * IN_F;         // N*32 fp16
    _Float16* H1h    = z + (size_t)N_NODES * IN_F;           // N*128 fp16
    _Float16* T2h    = H1h + (size_t)N_NODES * HID;          // N*128 fp16 (reused as T3)
    _Float16* H2h    = T2h + (size_t)N_NODES * HID;          // N*128 fp16

    const int xgrid = (N_NODES + 63) / 64;   // 1563

    // ---- CSR build (bucketed; no global per-node atomics) ----
    k_zero_bcnt<<<1, 256, 0, stream>>>(bcnt);
    k_bcount<<<NBB, 256, 0, stream>>>(dst, bcnt);
    k_bscan<<<1, 256, 0, stream>>>(bcnt, bbase, bcur);
    k_bucket<<<NBB, 256, 0, stream>>>(src, dst, bcur, rec);
    k_fill3<<<NBUCK, 256, 0, stream>>>(rec, bbase, ideg, cursor, col);

    // ---- layer 1 (aggregate-first; 32-dim gather, then MFMA 32->128) ----
    k_prescale<<<(N_NODES * 16 + 255) / 256, 256, 0, stream>>>(
        (const float2*)x, ideg, (__half2*)t1h);
    k_gather32<false, true><<<2048, 256, 0, stream>>>(
        cursor, ideg, col, t1h, nullptr, z);
    k_xform1_mfma<<<xgrid, 256, 0, stream>>>(z, W1, b1, H1h);

    // ---- layer 2 (MFMA 128->128, then 128-dim fp16 gather) ----
    k_xform2_mfma<<<xgrid, 256, 0, stream>>>(H1h, W2, ideg, T2h);
    k_gather128<<<2048, 256, 0, stream>>>(cursor, ideg, col, T2h, b2, H2h);

    // ---- layer 3 (MFMA 128->32, then 32-dim fp16 gather) ----
    k_xform3_mfma<<<xgrid, 256, 0, stream>>>(H2h, W3, ideg, T2h);
    k_gather32<true, false><<<2048, 256, 0, stream>>>(
        cursor, ideg, col, T2h, b3, out);
}